// Round 3
// baseline (182.533 us; speedup 1.0000x reference)
//
#include <hip/hip_runtime.h>

#define B_    4
#define N_    2048
#define HID_  768
#define NH_   12
#define E_    131072
#define M_    8192   // B_*N_
#define NREL_ 64
#define G_    16     // groups per attn block
#define BAND_ 32     // band width (K/V rows per block)
#define VP_   40     // Vt pitch in u16 (32 slots + 8 pad): 16B-aligned frags, spread banks
#define PP_   40     // p_bf pitch in u16

typedef unsigned short u16;
typedef unsigned int   u32;
typedef short bf16x8 __attribute__((ext_vector_type(8)));
typedef float f32x4  __attribute__((ext_vector_type(4)));

__device__ __forceinline__ u16 f2bf(float x) {
  u32 u = __float_as_uint(x);
  u += 0x7fffu + ((u >> 16) & 1u);   // RNE
  return (u16)(u >> 16);
}
__device__ __forceinline__ float bflo(u32 u) { return __uint_as_float(u << 16); }
__device__ __forceinline__ float bfhi(u32 u) { return __uint_as_float(u & 0xffff0000u); }
__device__ __forceinline__ float bf1(u16 v) { return __uint_as_float(((u32)v) << 16); }

__device__ __forceinline__ void load_lds16(const u16* g, u16* l) {
  __builtin_amdgcn_global_load_lds((__attribute__((address_space(1))) void*)(g),
                                   (__attribute__((address_space(3))) void*)(l),
                                   16, 0, 0);
}

// ---------------- Kernel 0: f32 -> bf16 convert (X, Wq, Wk, Wv, rel) ----------------
// HBM-roofline for its ~47MB of traffic. Frozen.
__global__ __launch_bounds__(256) void k_convert(
    const float4* __restrict__ X, const float4* __restrict__ Wq,
    const float4* __restrict__ Wk, const float4* __restrict__ Wv,
    const float4* __restrict__ rel,
    ushort4* __restrict__ Xbf, ushort4* __restrict__ Wbf, ushort4* __restrict__ Rbf) {
  const int NX4 = (M_ * HID_) / 4;
  const int NW4 = (HID_ * HID_) / 4;
  const int NR4 = (NREL_ * HID_) / 4;
  int tid = blockIdx.x * 256 + threadIdx.x;
  const float4* src; ushort4* dst; int off;
  if (tid < NX4) { src = X; dst = Xbf; off = tid; }
  else if (tid < NX4 + 3 * NW4) {
    int t2 = tid - NX4;
    int wi = t2 / NW4;
    off = t2 - wi * NW4;
    src = (wi == 0) ? Wq : (wi == 1) ? Wk : Wv;
    dst = Wbf + (size_t)wi * NW4;
  } else {
    off = tid - NX4 - 3 * NW4;
    if (off >= NR4) return;
    src = rel; dst = Rbf;
  }
  float4 v = src[off];
  ushort4 o;
  o.x = f2bf(v.x); o.y = f2bf(v.y); o.z = f2bf(v.z); o.w = f2bf(v.w);
  dst[off] = o;
}

// ---------------- Kernel 1: fused QKV GEMM, A-resident / B-streamed-from-L2 --------
// R11 restructure: K=768 is skinny and W (768x2304 bf16 = 3.5MB) is L2-resident per
// XCD, so B needs NO LDS staging: lanes load B-fragments DIRECTLY from global (L2),
// k_attn-style. Only A lives in LDS -- 64 rows x 768 K = 96KB, staged ONCE -> the
// K-loop has ZERO barriers / ZERO staging / ZERO inline asm. Reg-dbuf (a0/a1,b0/b1)
// + 2 waves/SIMD co-scheduling hide L2 latency. Block 64x1152, 8 waves (1x8), wave
// tile 64x144 (4x9 frags, 36 MFMA / 13 loads per K-step). Grid 128x2 = 256 = 1/CU.
// LDS layout [kt][m][chunk] keeps 64B row stride + ^((m>>1)&3) swizzle (measured
// 0 bank conflicts in R2) and a LINEAR global_load_lds dest with shift-only math.
__global__ __launch_bounds__(512, 2) void k_gemm(
    const u16* __restrict__ Xbf, const u16* __restrict__ Wbf,
    const float* __restrict__ bq, const float* __restrict__ bk, const float* __restrict__ bv,
    u16* __restrict__ Qb, u16* __restrict__ Kb, u16* __restrict__ Vb) {
  extern __shared__ __align__(16) u16 Alds[];   // [24 kt][64 m][4 q] 16B-chunks = 98304B
  const int tid = threadIdx.x;
  const int w = tid >> 6, lane = tid & 63;
  const int lm = lane & 15, lg = lane >> 4;
  const int m0   = blockIdx.x * 64;
  const int colb = blockIdx.y * 1152 + w * 144;   // fused col base (0..2303)

  // ---- Stage A panel once: linear LDS dest chunk d, swizzled source chunk ----
  // d = ii*512 + tid ; kt = d>>8, m = (d>>2)&63, stored q holds src chunk q^((m>>1)&3)
#pragma unroll
  for (int ii = 0; ii < 12; ++ii) {
    const int d  = ii * 512 + tid;
    const int kt = d >> 8;
    const int m  = (d >> 2) & 63;
    const int q  = (d & 3) ^ ((m >> 1) & 3);
    load_lds16(Xbf + (size_t)(m0 + m) * HID_ + kt * 32 + q * 8, Alds + (size_t)d * 8);
  }
  __syncthreads();   // one-time drain; A stays resident for the whole K-loop

  // Per-lane A frag base: row lm, swizzled chunk (swz(m)=(lm>>1)&3 since mt*16 ~ 0 mod 8)
  const u16* Abase = Alds + lm * 32 + (lg ^ ((lm >> 1) & 3)) * 8;  // + kt*2048 + mt*512
  // Per-lane B frag base: col (colb + lm), k-chunk lg  (B^T row-major [n][k])
  const u16* wp = Wbf + (size_t)(colb + lm) * HID_ + lg * 8;       // + nt*16*HID_ + kt*32

  f32x4 acc[4][9] = {};
  bf16x8 a0[4], a1[4], b0[9], b1[9];

#define LOADA(DST, KT) { _Pragma("unroll") for (int mt = 0; mt < 4; ++mt)        \
    DST[mt] = *(const bf16x8*)(Abase + (KT) * 2048 + mt * 512); }
#define LOADB(DST, KT) { _Pragma("unroll") for (int nt = 0; nt < 9; ++nt)        \
    DST[nt] = *(const bf16x8*)(wp + (size_t)nt * (16 * HID_) + (KT) * 32); }
#define MM(AA, BB) { _Pragma("unroll") for (int mt = 0; mt < 4; ++mt)            \
    _Pragma("unroll") for (int nt = 0; nt < 9; ++nt)                             \
      acc[mt][nt] = __builtin_amdgcn_mfma_f32_16x16x32_bf16(AA[mt], BB[nt], acc[mt][nt], 0, 0, 0); }

  LOADA(a0, 0); LOADB(b0, 0);
  for (int i = 0; i < 11; ++i) {
    const int k1 = 2 * i + 1;
    LOADA(a1, k1); LOADB(b1, k1);        // prefetch odd step
    MM(a0, b0);                          // compute even step (hides b1/a1 latency)
    LOADA(a0, k1 + 1); LOADB(b0, k1 + 1);
    MM(a1, b1);
  }
  LOADA(a1, 23); LOADB(b1, 23);
  MM(a0, b0);
  MM(a1, b1);

#undef MM
#undef LOADB
#undef LOADA

  // Epilogue: fused col -> (widx, local col). colb + nt*16 is a multiple of 16 and
  // 768-boundaries are too, so widx is uniform per (wave, nt) fragment.
#pragma unroll
  for (int nt = 0; nt < 9; ++nt) {
    const int c    = colb + nt * 16 + lm;
    const int widx = (c >= 1536) ? 2 : (c >= 768) ? 1 : 0;
    const int col  = c - widx * 768;
    const float bb = ((widx == 0) ? bq : (widx == 1) ? bk : bv)[col];
    u16* Op = (widx == 0) ? Qb : (widx == 1) ? Kb : Vb;
#pragma unroll
    for (int mt = 0; mt < 4; ++mt) {
      const int rbase = m0 + mt * 16 + lg * 4;
#pragma unroll
      for (int r = 0; r < 4; ++r)
        Op[(size_t)(rbase + r) * HID_ + col] = f2bf(acc[mt][nt][r] + bb);
    }
  }
}

// ---------------- Kernel 1b: QRel[(b,i)][h*64+r] = Q[b,i,h,:]·rel[r,h,:] ----------------
__global__ __launch_bounds__(256) void k_qrel(
    const u16* __restrict__ Qb, const u16* __restrict__ Rbf, u16* __restrict__ QRelb) {
  const int tid = threadIdx.x, w = tid >> 6, lane = tid & 63;
  const int lm = lane & 15, quad = lane >> 4;
  const int m0 = blockIdx.x * 32 + (w & 1) * 16;
  const int h0 = (w >> 1) * 6;
#pragma unroll
  for (int hh = 0; hh < 6; ++hh) {
    const int h = h0 + hh;
    const u16* qp = Qb + (size_t)(m0 + lm) * HID_ + h * 64 + quad * 8;
    bf16x8 a0 = *(const bf16x8*)(qp);
    bf16x8 a1 = *(const bf16x8*)(qp + 32);
#pragma unroll
    for (int rt = 0; rt < 4; ++rt) {
      const u16* rp = Rbf + (size_t)(rt * 16 + lm) * HID_ + h * 64 + quad * 8;
      bf16x8 b0 = *(const bf16x8*)(rp);
      bf16x8 b1 = *(const bf16x8*)(rp + 32);
      f32x4 c = {0.f, 0.f, 0.f, 0.f};
      c = __builtin_amdgcn_mfma_f32_16x16x32_bf16(a0, b0, c, 0, 0, 0);
      c = __builtin_amdgcn_mfma_f32_16x16x32_bf16(a1, b1, c, 0, 0, 0);
#pragma unroll
      for (int r = 0; r < 4; ++r)
        QRelb[(size_t)(m0 + quad * 4 + r) * HID_ + h * 64 + rt * 16 + lm] = f2bf(c[r]);
    }
  }
}

// ---------------- Kernel 2: banded attention, single-window 2-barrier ----------------
// R8 restructure: no K LDS staging at all. Heads partition the dims, so each
// (K-row, 16B dim-chunk) is consumed by exactly one (wave, head): lanes load
// their QK B-fragments DIRECTLY from global (same total bytes as staging,
// zero LDS round-trip). All global loads (V rows -> 48 VGPR, K frags -> 72,
// Q frags -> 24) issue before barrier A, which also publishes r_s/t_s/badf/
// p_bf-zero -> ONE vmcnt drain for the whole kernel. After barrier A all data
// is in registers: Vt scatter + QK MFMA + softmax -> p_bf, barrier B, PV MFMA.
__global__ __launch_bounds__(256, 2) void k_attn(
    const u16* __restrict__ Qb, const u16* __restrict__ Kb, const u16* __restrict__ Vb,
    const u16* __restrict__ QRelb, const int* __restrict__ eidx,
    float* __restrict__ out) {
  __shared__ __align__(16) u16 Vt[HID_ * VP_];       // 61,440B
  __shared__ __align__(16) u16 p_bf[NH_ * 16 * PP_]; // 15,360B
  __shared__ u16 r_s[256];
  __shared__ int t_s[256];
  __shared__ int badf;

  const int tid = threadIdx.x;
  const int w = tid >> 6, lane = tid & 63;
  const int lm = lane & 15, quad = lane >> 4;
  const int e0b = blockIdx.x * 256;
  const int b  = eidx[e0b];
  const int i0 = eidx[E_ + e0b];
  const int bN = b * N_;

  // ---- V prefetch into VGPRs (48 VGPR), transpose-store mapping ----
  const int sV = tid & 31, pV = tid >> 5;
  const int rowV = (i0 + 1 + sV) & (N_ - 1);
  const u16* srcV = Vb + (size_t)(bN + rowV) * HID_ + pV * 96;
  uint4 vv[12];
#pragma unroll
  for (int c = 0; c < 12; ++c) vv[c] = *(const uint4*)(srcV + c * 8);

  // ---- Q + K fragments direct from global (B-frag layout, 16B/lane) ----
  const u16* Qrow  = Qb + (size_t)(bN + i0 + lm) * HID_ + quad * 8;
  const u16* Krow0 = Kb + (size_t)(bN + ((i0 + 1 + lm) & (N_ - 1))) * HID_ + quad * 8;
  const u16* Krow1 = Kb + (size_t)(bN + ((i0 + 17 + lm) & (N_ - 1))) * HID_ + quad * 8;
  bf16x8 qa[3][2], ka[3][4];
#pragma unroll
  for (int hh = 0; hh < 3; ++hh) {
    const int o = (w * 3 + hh) * 64;
    qa[hh][0] = *(const bf16x8*)(Qrow + o);
    qa[hh][1] = *(const bf16x8*)(Qrow + o + 32);
    ka[hh][0] = *(const bf16x8*)(Krow0 + o);
    ka[hh][1] = *(const bf16x8*)(Krow0 + o + 32);
    ka[hh][2] = *(const bf16x8*)(Krow1 + o);
    ka[hh][3] = *(const bf16x8*)(Krow1 + o + 32);
  }

  // ---- P0: publish t/r, zero p_bf, band-pattern check ----
  const int t_own = eidx[2 * E_ + e0b + tid];
  const int r_own = eidx[3 * E_ + e0b + tid];
  t_s[tid] = t_own;
  r_s[tid] = (u16)r_own;
  if (tid == 0) badf = 0;
  {
    u32* pz = (u32*)p_bf;
#pragma unroll
    for (int z = 0; z < NH_ * 16 * PP_ / 2 / 256; ++z) pz[z * 256 + tid] = 0;
    const int expect = (i0 + (tid >> 4) + (tid & 15) + 1) & (N_ - 1);
    if (t_own != expect) badf = 1;
  }
  __syncthreads();   // barrier A: publishes LDS + drains ALL global loads
  const int bad = badf;

  if (!bad) {
    // ---- Vt scatter from registers (2-way banks, free) ----
#pragma unroll
    for (int c = 0; c < 12; ++c) {
      uint4 v = vv[c];
      const int d0 = pV * 96 + c * 8;
      Vt[(d0 + 0) * VP_ + sV] = (u16)(v.x);
      Vt[(d0 + 1) * VP_ + sV] = (u16)(v.x >> 16);
      Vt[(d0 + 2) * VP_ + sV] = (u16)(v.y);
      Vt[(d0 + 3) * VP_ + sV] = (u16)(v.y >> 16);
      Vt[(d0 + 4) * VP_ + sV] = (u16)(v.z);
      Vt[(d0 + 5) * VP_ + sV] = (u16)(v.z >> 16);
      Vt[(d0 + 6) * VP_ + sV] = (u16)(v.w);
      Vt[(d0 + 7) * VP_ + sV] = (u16)(v.w >> 16);
    }

    // ---- QRel gather (r_s now visible; L2-resident) ----
    int eidx4[4]; float qrelv[3][4];
#pragma unroll
    for (int r = 0; r < 4; ++r) {
      const int il = quad * 4 + r;
      eidx4[r] = il * 16 + ((lm - il) & 15);
    }
#pragma unroll
    for (int hh = 0; hh < 3; ++hh) {
      const int h = w * 3 + hh;
#pragma unroll
      for (int r = 0; r < 4; ++r) {
        const int il = quad * 4 + r;
        qrelv[hh][r] = bf1(QRelb[(size_t)(bN + i0 + il) * HID_ + h * 64 + r_s[eidx4[r]]]);
      }
    }

    // ---- QK^T MFMA (all-register operands) + in-register softmax -> p_bf ----
#pragma unroll
    for (int hh = 0; hh < 3; ++hh) {
      const int h = w * 3 + hh;
      f32x4 c0 = {0.f, 0.f, 0.f, 0.f}, c1 = {0.f, 0.f, 0.f, 0.f};
      c0 = __builtin_amdgcn_mfma_f32_16x16x32_bf16(qa[hh][0], ka[hh][0], c0, 0, 0, 0);
      c0 = __builtin_amdgcn_mfma_f32_16x16x32_bf16(qa[hh][1], ka[hh][1], c0, 0, 0, 0);
      c1 = __builtin_amdgcn_mfma_f32_16x16x32_bf16(qa[hh][0], ka[hh][2], c1, 0, 0, 0);
      c1 = __builtin_amdgcn_mfma_f32_16x16x32_bf16(qa[hh][1], ka[hh][3], c1, 0, 0, 0);
#pragma unroll
      for (int r = 0; r < 4; ++r) {
        const int il = quad * 4 + r;
        const float val = (lm >= il) ? c0[r] : c1[r];
        const float ex = __expf((val - qrelv[hh][r]) * 0.125f);
        float den = ex;
        den += __shfl_xor(den, 1);
        den += __shfl_xor(den, 2);
        den += __shfl_xor(den, 4);
        den += __shfl_xor(den, 8);
        const float p = ex * __builtin_amdgcn_rcpf(den);
        const int slot = il + ((lm - il) & 15);
        p_bf[(h * 16 + il) * PP_ + slot] = f2bf(p);
      }
    }
    __syncthreads();   // barrier B: Vt + p_bf complete

    // ---- PV: out = P @ Vband via MFMA ----
#pragma unroll
    for (int hh = 0; hh < 3; ++hh) {
      const int h = w * 3 + hh;
      bf16x8 af = *(const bf16x8*)&p_bf[(h * 16 + lm) * PP_ + quad * 8];
#pragma unroll
      for (int nt = 0; nt < 4; ++nt) {
        bf16x8 bv = *(const bf16x8*)&Vt[(h * 64 + nt * 16 + lm) * VP_ + quad * 8];
        f32x4 d = {0.f, 0.f, 0.f, 0.f};
        d = __builtin_amdgcn_mfma_f32_16x16x32_bf16(af, bv, d, 0, 0, 0);
#pragma unroll
        for (int r = 0; r < 4; ++r)
          out[(size_t)(bN + i0 + quad * 4 + r) * HID_ + h * 64 + nt * 16 + lm] = d[r];
      }
    }
  } else {
    // ---- Fallback (block-uniform; never taken for reference edge pattern) ----
    const int il = tid >> 4;
#pragma unroll
    for (int h = 0; h < NH_; ++h) {
      const u16* qp = Qb + (size_t)(bN + i0 + il) * HID_ + h * 64;
      const u16* kp = Kb + (size_t)(bN + t_own) * HID_ + h * 64;
      float s = 0.f;
      for (int d = 0; d < 64; ++d) s += bf1(qp[d]) * bf1(kp[d]);
      const float qrel = bf1(QRelb[(size_t)(bN + i0 + il) * HID_ + h * 64 + r_own]);
      const float ex = __expf((s - qrel) * 0.125f);
      float den = ex;
      den += __shfl_xor(den, 1);
      den += __shfl_xor(den, 2);
      den += __shfl_xor(den, 4);
      den += __shfl_xor(den, 8);
      p_bf[tid * NH_ + h] = f2bf(ex * __builtin_amdgcn_rcpf(den));
    }
    __syncthreads();
#pragma unroll
    for (int gsub = 0; gsub < 4; ++gsub) {
      const int il2 = w * 4 + gsub;
      float a0[8] = {0.f,0.f,0.f,0.f,0.f,0.f,0.f,0.f};
      float a1[8] = {0.f,0.f,0.f,0.f,0.f,0.f,0.f,0.f};
      for (int j2 = 0; j2 < 16; ++j2) {
        const int t2 = t_s[il2 * 16 + j2];
        const u16* Vrow = Vb + (size_t)(bN + t2) * HID_;
        uint4 v0 = *(const uint4*)(Vrow + lane * 8);
        const float p0 = bf1(p_bf[(il2 * 16 + j2) * NH_ + (lane >> 3)]);
        a0[0] += p0 * bflo(v0.x); a0[1] += p0 * bfhi(v0.x);
        a0[2] += p0 * bflo(v0.y); a0[3] += p0 * bfhi(v0.y);
        a0[4] += p0 * bflo(v0.z); a0[5] += p0 * bfhi(v0.z);
        a0[6] += p0 * bflo(v0.w); a0[7] += p0 * bfhi(v0.w);
        if (lane < 32) {
          uint4 v1 = *(const uint4*)(Vrow + 512 + lane * 8);
          const float p1 = bf1(p_bf[(il2 * 16 + j2) * NH_ + 8 + (lane >> 3)]);
          a1[0] += p1 * bflo(v1.x); a1[1] += p1 * bfhi(v1.x);
          a1[2] += p1 * bflo(v1.y); a1[3] += p1 * bfhi(v1.y);
          a1[4] += p1 * bflo(v1.z); a1[5] += p1 * bfhi(v1.z);
          a1[6] += p1 * bflo(v1.w); a1[7] += p1 * bfhi(v1.w);
        }
      }
      float* orow = out + (size_t)(bN + i0 + il2) * HID_;
      *(float4*)(orow + lane * 8)     = make_float4(a0[0], a0[1], a0[2], a0[3]);
      *(float4*)(orow + lane * 8 + 4) = make_float4(a0[4], a0[5], a0[6], a0[7]);
      if (lane < 32) {
        *(float4*)(orow + 512 + lane * 8)     = make_float4(a1[0], a1[1], a1[2], a1[3]);
        *(float4*)(orow + 512 + lane * 8 + 4) = make_float4(a1[4], a1[5], a1[6], a1[7]);
      }
    }
  }
}

extern "C" void kernel_launch(void* const* d_in, const int* in_sizes, int n_in,
                              void* d_out, int out_size, void* d_ws, size_t ws_size,
                              hipStream_t stream) {
  const float* X   = (const float*)d_in[0];
  const int*   eidx= (const int*)d_in[1];
  const float* Wq  = (const float*)d_in[2];
  const float* bq  = (const float*)d_in[3];
  const float* Wk  = (const float*)d_in[4];
  const float* bk  = (const float*)d_in[5];
  const float* Wv  = (const float*)d_in[6];
  const float* bv  = (const float*)d_in[7];
  const float* rel = (const float*)d_in[8];
  float* out = (float*)d_out;

  char* ws = (char*)d_ws;
  u16* Xbf = (u16*)(ws);
  u16* QRelb = Xbf;                       // overlays Xbf (dead after k_gemm)
  u16* Wbf = (u16*)(ws + 12582912);
  u16* Qb  = (u16*)(ws + 16121856);
  u16* Kb  = (u16*)(ws + 28704768);
  u16* Vb  = (u16*)(ws + 41287680);
  u16* Rbf = (u16*)(ws + 53870592);

  static bool s_attr = false;
  if (!s_attr) {
    (void)hipFuncSetAttribute((const void*)k_gemm,
                              hipFuncAttributeMaxDynamicSharedMemorySize, 98304);
    s_attr = true;
  }

  k_convert<<<7920, 256, 0, stream>>>((const float4*)X, (const float4*)Wq,
                                      (const float4*)Wk, (const float4*)Wv,
                                      (const float4*)rel,
                                      (ushort4*)Xbf, (ushort4*)Wbf, (ushort4*)Rbf);
  k_gemm<<<dim3(128, 2), 512, 98304, stream>>>(Xbf, Wbf, bq, bk, bv, Qb, Kb, Vb);
  k_qrel<<<256, 256, 0, stream>>>(Qb, Rbf, QRelb);
  k_attn<<<512, 256, 0, stream>>>(Qb, Kb, Vb, QRelb, eidx, out);
}

// Round 4
// 162.914 us; speedup vs baseline: 1.1204x; 1.1204x over previous
//
#include <hip/hip_runtime.h>

#define B_    4
#define N_    2048
#define HID_  768
#define NH_   12
#define E_    131072
#define M_    8192   // B_*N_
#define NREL_ 64
#define G_    16     // groups per attn block
#define BAND_ 32     // band width (K/V rows per block)
#define VP_   40     // Vt pitch in u16 (32 slots + 8 pad): 16B-aligned frags, spread banks
#define PP_   40     // p_bf pitch in u16

typedef unsigned short u16;
typedef unsigned int   u32;
typedef short bf16x8 __attribute__((ext_vector_type(8)));
typedef float f32x4  __attribute__((ext_vector_type(4)));

__device__ __forceinline__ u16 f2bf(float x) {
  u32 u = __float_as_uint(x);
  u += 0x7fffu + ((u >> 16) & 1u);   // RNE
  return (u16)(u >> 16);
}
__device__ __forceinline__ float bflo(u32 u) { return __uint_as_float(u << 16); }
__device__ __forceinline__ float bfhi(u32 u) { return __uint_as_float(u & 0xffff0000u); }
__device__ __forceinline__ float bf1(u16 v) { return __uint_as_float(((u32)v) << 16); }

__device__ __forceinline__ void load_lds16(const u16* g, u16* l) {
  __builtin_amdgcn_global_load_lds((__attribute__((address_space(1))) void*)(g),
                                   (__attribute__((address_space(3))) void*)(l),
                                   16, 0, 0);
}

// ---------------- Kernel 0: f32 -> bf16 convert (X, Wq, Wk, Wv, rel) ----------------
// HBM-roofline for its ~47MB of traffic. Frozen.
__global__ __launch_bounds__(256) void k_convert(
    const float4* __restrict__ X, const float4* __restrict__ Wq,
    const float4* __restrict__ Wk, const float4* __restrict__ Wv,
    const float4* __restrict__ rel,
    ushort4* __restrict__ Xbf, ushort4* __restrict__ Wbf, ushort4* __restrict__ Rbf) {
  const int NX4 = (M_ * HID_) / 4;
  const int NW4 = (HID_ * HID_) / 4;
  const int NR4 = (NREL_ * HID_) / 4;
  int tid = blockIdx.x * 256 + threadIdx.x;
  const float4* src; ushort4* dst; int off;
  if (tid < NX4) { src = X; dst = Xbf; off = tid; }
  else if (tid < NX4 + 3 * NW4) {
    int t2 = tid - NX4;
    int wi = t2 / NW4;
    off = t2 - wi * NW4;
    src = (wi == 0) ? Wq : (wi == 1) ? Wk : Wv;
    dst = Wbf + (size_t)wi * NW4;
  } else {
    off = tid - NX4 - 3 * NW4;
    if (off >= NR4) return;
    src = rel; dst = Rbf;
  }
  float4 v = src[off];
  ushort4 o;
  o.x = f2bf(v.x); o.y = f2bf(v.y); o.z = f2bf(v.z); o.w = f2bf(v.w);
  dst[off] = o;
}

// ---------------- Kernel 1: fused QKV GEMM, m201-style barrier-paired phases -------
// R12: faithful 8-phase-template port (m201 class). BM=256 x BN=288 (fused N=2304),
// BK=64, dbuf=2 (139,264B LDS -> 1 block/CU), 512 thr, 8 waves 4m x 2n (wave tile
// 64x144). Per K-tile, TWO phases (kk=0/1), each {13 plain ds_read_b128 + stage
// issue OUTSIDE; s_barrier; setprio(1); 36 MFMA; setprio(0); s_barrier}. All of
// tile t+1's stage loads issue in t's P1; the single vmcnt(0) sits in t's P2 with
// a full MFMA phase of cover (draining long-issued loads is free). NO sched_barrier,
// NO per-phase memory clobbers (R2's mistake, m141 class) -- compiler schedules
// ds_read->MFMA lgkm waits itself. Swizzle: chunk ^= row&7 on 128B rows -> uniform
// 32B/bank per b128 read (0 conflicts measured for this class in R2).
__global__ __launch_bounds__(512, 2) void k_gemm(
    const u16* __restrict__ Xbf, const u16* __restrict__ Wbf,
    const float* __restrict__ bq, const float* __restrict__ bk, const float* __restrict__ bv,
    u16* __restrict__ Qb, u16* __restrict__ Kb, u16* __restrict__ Vb) {
  extern __shared__ __align__(16) u16 lds[];   // 2 x (256 A + 288 B rows) x 64 K x 2B
  const int tid = threadIdx.x;
  const int w = tid >> 6, lane = tid & 63;
  const int lm = lane & 15, lg = lane >> 4;
  const int wm = w >> 1, wn = w & 1;           // 4x2 wave grid
  const int m0  = blockIdx.x * 256;
  const int n0g = blockIdx.y * 288;            // fused col base (0..2303)

  f32x4 acc[4][9] = {};

// Stage tile KT into buffer BI: linear LDS dest chunk d, source chunk (d&7)^(row&7).
// 8 loads/thread (+1 for tid<256 covering B rows 256..287).
#define STAGE_TILE(BI, KT) do {                                             \
    u16* Ab_ = lds + (BI) * 34816;                                          \
    u16* Bb_ = lds + (BI) * 34816 + 16384;                                  \
    const int k0_ = (KT) * 64;                                              \
    _Pragma("unroll")                                                       \
    for (int ii = 0; ii < 4; ++ii) {                                        \
      const int d = ii * 512 + tid;                                         \
      const int m = d >> 3;                                                 \
      const int q = (d & 7) ^ (m & 7);                                      \
      load_lds16(Xbf + (size_t)(m0 + m) * HID_ + k0_ + q * 8, Ab_ + d * 8); \
    }                                                                       \
    _Pragma("unroll")                                                       \
    for (int ii = 0; ii < 4; ++ii) {                                        \
      const int d = ii * 512 + tid;                                         \
      const int n = d >> 3;                                                 \
      const int q = (d & 7) ^ (n & 7);                                      \
      load_lds16(Wbf + (size_t)(n0g + n) * HID_ + k0_ + q * 8, Bb_ + d * 8);\
    }                                                                       \
    if (tid < 256) {                                                        \
      const int d = 2048 + tid;                                             \
      const int n = d >> 3;                                                 \
      const int q = (d & 7) ^ (n & 7);                                      \
      load_lds16(Wbf + (size_t)(n0g + n) * HID_ + k0_ + q * 8, Bb_ + d * 8);\
    }                                                                       \
  } while (0)

#define READA(DST, AS, KK) { _Pragma("unroll")                              \
    for (int mt = 0; mt < 4; ++mt) {                                        \
      const int m_ = wm * 64 + mt * 16 + lm;                                \
      const int c_ = ((KK) * 4 + lg) ^ (m_ & 7);                            \
      DST[mt] = *(const bf16x8*)&(AS)[m_ * 64 + c_ * 8];                    \
    } }
#define READB(DST, BS, KK) { _Pragma("unroll")                              \
    for (int nt = 0; nt < 9; ++nt) {                                        \
      const int n_ = wn * 144 + nt * 16 + lm;                               \
      const int c_ = ((KK) * 4 + lg) ^ (n_ & 7);                            \
      DST[nt] = *(const bf16x8*)&(BS)[n_ * 64 + c_ * 8];                    \
    } }
#define MM(AA, BB) { _Pragma("unroll") for (int mt = 0; mt < 4; ++mt)       \
    _Pragma("unroll") for (int nt = 0; nt < 9; ++nt)                        \
      acc[mt][nt] = __builtin_amdgcn_mfma_f32_16x16x32_bf16(AA[mt], BB[nt], acc[mt][nt], 0, 0, 0); }

// Barrier with free compiler fences (keeps memory ops in their phase; no runtime cost)
#define FBAR() do { asm volatile("" ::: "memory");                          \
                    __builtin_amdgcn_s_barrier();                           \
                    asm volatile("" ::: "memory"); } while (0)

  // Prologue: stage tile 0, drain, sync.
  STAGE_TILE(0, 0);
  asm volatile("s_waitcnt vmcnt(0)" ::: "memory");
  FBAR();

  for (int t = 0; t < 12; ++t) {
    const u16* As = lds + (t & 1) * 34816;
    const u16* Bs = As + 16384;
    // ---- P1 (kk=0): reads + all of tile t+1's stage issues, then MFMA window ----
    bf16x8 a0[4], b0[9];
    READA(a0, As, 0); READB(b0, Bs, 0);
    if (t < 11) STAGE_TILE((t & 1) ^ 1, t + 1);
    FBAR();
    __builtin_amdgcn_s_setprio(1);
    MM(a0, b0);
    __builtin_amdgcn_s_setprio(0);
    FBAR();
    // ---- P2 (kk=1): reads, covered drain of t+1's stage, MFMA window ----
    bf16x8 a1[4], b1[9];
    READA(a1, As, 1); READB(b1, Bs, 1);
    if (t < 11) asm volatile("s_waitcnt vmcnt(0)" ::: "memory");  // >=1 phase of cover
    FBAR();
    __builtin_amdgcn_s_setprio(1);
    MM(a1, b1);
    __builtin_amdgcn_s_setprio(0);
    FBAR();
  }

#undef FBAR
#undef MM
#undef READB
#undef READA
#undef STAGE_TILE

  // Epilogue: fused col -> (widx, local col). 16-col runs never straddle a 768
  // boundary (all bases multiple of 16), so widx is uniform per (wave, nt) fragment.
#pragma unroll
  for (int nt = 0; nt < 9; ++nt) {
    const int c    = n0g + wn * 144 + nt * 16 + lm;
    const int widx = (c >= 1536) ? 2 : (c >= 768) ? 1 : 0;
    const int col  = c - widx * 768;
    const float bb = ((widx == 0) ? bq : (widx == 1) ? bk : bv)[col];
    u16* Op = (widx == 0) ? Qb : (widx == 1) ? Kb : Vb;
#pragma unroll
    for (int mt = 0; mt < 4; ++mt) {
      const int rbase = m0 + wm * 64 + mt * 16 + lg * 4;
#pragma unroll
      for (int r = 0; r < 4; ++r)
        Op[(size_t)(rbase + r) * HID_ + col] = f2bf(acc[mt][nt][r] + bb);
    }
  }
}

// ---------------- Kernel 1b: QRel[(b,i)][h*64+r] = Q[b,i,h,:]·rel[r,h,:] ----------------
__global__ __launch_bounds__(256) void k_qrel(
    const u16* __restrict__ Qb, const u16* __restrict__ Rbf, u16* __restrict__ QRelb) {
  const int tid = threadIdx.x, w = tid >> 6, lane = tid & 63;
  const int lm = lane & 15, quad = lane >> 4;
  const int m0 = blockIdx.x * 32 + (w & 1) * 16;
  const int h0 = (w >> 1) * 6;
#pragma unroll
  for (int hh = 0; hh < 6; ++hh) {
    const int h = h0 + hh;
    const u16* qp = Qb + (size_t)(m0 + lm) * HID_ + h * 64 + quad * 8;
    bf16x8 a0 = *(const bf16x8*)(qp);
    bf16x8 a1 = *(const bf16x8*)(qp + 32);
#pragma unroll
    for (int rt = 0; rt < 4; ++rt) {
      const u16* rp = Rbf + (size_t)(rt * 16 + lm) * HID_ + h * 64 + quad * 8;
      bf16x8 b0 = *(const bf16x8*)(rp);
      bf16x8 b1 = *(const bf16x8*)(rp + 32);
      f32x4 c = {0.f, 0.f, 0.f, 0.f};
      c = __builtin_amdgcn_mfma_f32_16x16x32_bf16(a0, b0, c, 0, 0, 0);
      c = __builtin_amdgcn_mfma_f32_16x16x32_bf16(a1, b1, c, 0, 0, 0);
#pragma unroll
      for (int r = 0; r < 4; ++r)
        QRelb[(size_t)(m0 + quad * 4 + r) * HID_ + h * 64 + rt * 16 + lm] = f2bf(c[r]);
    }
  }
}

// ---------------- Kernel 2: banded attention, single-window 2-barrier ----------------
// R8 restructure: no K LDS staging at all. Heads partition the dims, so each
// (K-row, 16B dim-chunk) is consumed by exactly one (wave, head): lanes load
// their QK B-fragments DIRECTLY from global (same total bytes as staging,
// zero LDS round-trip). All global loads (V rows -> 48 VGPR, K frags -> 72,
// Q frags -> 24) issue before barrier A, which also publishes r_s/t_s/badf/
// p_bf-zero -> ONE vmcnt drain for the whole kernel. After barrier A all data
// is in registers: Vt scatter + QK MFMA + softmax -> p_bf, barrier B, PV MFMA.
__global__ __launch_bounds__(256, 2) void k_attn(
    const u16* __restrict__ Qb, const u16* __restrict__ Kb, const u16* __restrict__ Vb,
    const u16* __restrict__ QRelb, const int* __restrict__ eidx,
    float* __restrict__ out) {
  __shared__ __align__(16) u16 Vt[HID_ * VP_];       // 61,440B
  __shared__ __align__(16) u16 p_bf[NH_ * 16 * PP_]; // 15,360B
  __shared__ u16 r_s[256];
  __shared__ int t_s[256];
  __shared__ int badf;

  const int tid = threadIdx.x;
  const int w = tid >> 6, lane = tid & 63;
  const int lm = lane & 15, quad = lane >> 4;
  const int e0b = blockIdx.x * 256;
  const int b  = eidx[e0b];
  const int i0 = eidx[E_ + e0b];
  const int bN = b * N_;

  // ---- V prefetch into VGPRs (48 VGPR), transpose-store mapping ----
  const int sV = tid & 31, pV = tid >> 5;
  const int rowV = (i0 + 1 + sV) & (N_ - 1);
  const u16* srcV = Vb + (size_t)(bN + rowV) * HID_ + pV * 96;
  uint4 vv[12];
#pragma unroll
  for (int c = 0; c < 12; ++c) vv[c] = *(const uint4*)(srcV + c * 8);

  // ---- Q + K fragments direct from global (B-frag layout, 16B/lane) ----
  const u16* Qrow  = Qb + (size_t)(bN + i0 + lm) * HID_ + quad * 8;
  const u16* Krow0 = Kb + (size_t)(bN + ((i0 + 1 + lm) & (N_ - 1))) * HID_ + quad * 8;
  const u16* Krow1 = Kb + (size_t)(bN + ((i0 + 17 + lm) & (N_ - 1))) * HID_ + quad * 8;
  bf16x8 qa[3][2], ka[3][4];
#pragma unroll
  for (int hh = 0; hh < 3; ++hh) {
    const int o = (w * 3 + hh) * 64;
    qa[hh][0] = *(const bf16x8*)(Qrow + o);
    qa[hh][1] = *(const bf16x8*)(Qrow + o + 32);
    ka[hh][0] = *(const bf16x8*)(Krow0 + o);
    ka[hh][1] = *(const bf16x8*)(Krow0 + o + 32);
    ka[hh][2] = *(const bf16x8*)(Krow1 + o);
    ka[hh][3] = *(const bf16x8*)(Krow1 + o + 32);
  }

  // ---- P0: publish t/r, zero p_bf, band-pattern check ----
  const int t_own = eidx[2 * E_ + e0b + tid];
  const int r_own = eidx[3 * E_ + e0b + tid];
  t_s[tid] = t_own;
  r_s[tid] = (u16)r_own;
  if (tid == 0) badf = 0;
  {
    u32* pz = (u32*)p_bf;
#pragma unroll
    for (int z = 0; z < NH_ * 16 * PP_ / 2 / 256; ++z) pz[z * 256 + tid] = 0;
    const int expect = (i0 + (tid >> 4) + (tid & 15) + 1) & (N_ - 1);
    if (t_own != expect) badf = 1;
  }
  __syncthreads();   // barrier A: publishes LDS + drains ALL global loads
  const int bad = badf;

  if (!bad) {
    // ---- Vt scatter from registers (2-way banks, free) ----
#pragma unroll
    for (int c = 0; c < 12; ++c) {
      uint4 v = vv[c];
      const int d0 = pV * 96 + c * 8;
      Vt[(d0 + 0) * VP_ + sV] = (u16)(v.x);
      Vt[(d0 + 1) * VP_ + sV] = (u16)(v.x >> 16);
      Vt[(d0 + 2) * VP_ + sV] = (u16)(v.y);
      Vt[(d0 + 3) * VP_ + sV] = (u16)(v.y >> 16);
      Vt[(d0 + 4) * VP_ + sV] = (u16)(v.z);
      Vt[(d0 + 5) * VP_ + sV] = (u16)(v.z >> 16);
      Vt[(d0 + 6) * VP_ + sV] = (u16)(v.w);
      Vt[(d0 + 7) * VP_ + sV] = (u16)(v.w >> 16);
    }

    // ---- QRel gather (r_s now visible; L2-resident) ----
    int eidx4[4]; float qrelv[3][4];
#pragma unroll
    for (int r = 0; r < 4; ++r) {
      const int il = quad * 4 + r;
      eidx4[r] = il * 16 + ((lm - il) & 15);
    }
#pragma unroll
    for (int hh = 0; hh < 3; ++hh) {
      const int h = w * 3 + hh;
#pragma unroll
      for (int r = 0; r < 4; ++r) {
        const int il = quad * 4 + r;
        qrelv[hh][r] = bf1(QRelb[(size_t)(bN + i0 + il) * HID_ + h * 64 + r_s[eidx4[r]]]);
      }
    }

    // ---- QK^T MFMA (all-register operands) + in-register softmax -> p_bf ----
#pragma unroll
    for (int hh = 0; hh < 3; ++hh) {
      const int h = w * 3 + hh;
      f32x4 c0 = {0.f, 0.f, 0.f, 0.f}, c1 = {0.f, 0.f, 0.f, 0.f};
      c0 = __builtin_amdgcn_mfma_f32_16x16x32_bf16(qa[hh][0], ka[hh][0], c0, 0, 0, 0);
      c0 = __builtin_amdgcn_mfma_f32_16x16x32_bf16(qa[hh][1], ka[hh][1], c0, 0, 0, 0);
      c1 = __builtin_amdgcn_mfma_f32_16x16x32_bf16(qa[hh][0], ka[hh][2], c1, 0, 0, 0);
      c1 = __builtin_amdgcn_mfma_f32_16x16x32_bf16(qa[hh][1], ka[hh][3], c1, 0, 0, 0);
#pragma unroll
      for (int r = 0; r < 4; ++r) {
        const int il = quad * 4 + r;
        const float val = (lm >= il) ? c0[r] : c1[r];
        const float ex = __expf((val - qrelv[hh][r]) * 0.125f);
        float den = ex;
        den += __shfl_xor(den, 1);
        den += __shfl_xor(den, 2);
        den += __shfl_xor(den, 4);
        den += __shfl_xor(den, 8);
        const float p = ex * __builtin_amdgcn_rcpf(den);
        const int slot = il + ((lm - il) & 15);
        p_bf[(h * 16 + il) * PP_ + slot] = f2bf(p);
      }
    }
    __syncthreads();   // barrier B: Vt + p_bf complete

    // ---- PV: out = P @ Vband via MFMA ----
#pragma unroll
    for (int hh = 0; hh < 3; ++hh) {
      const int h = w * 3 + hh;
      bf16x8 af = *(const bf16x8*)&p_bf[(h * 16 + lm) * PP_ + quad * 8];
#pragma unroll
      for (int nt = 0; nt < 4; ++nt) {
        bf16x8 bv = *(const bf16x8*)&Vt[(h * 64 + nt * 16 + lm) * VP_ + quad * 8];
        f32x4 d = {0.f, 0.f, 0.f, 0.f};
        d = __builtin_amdgcn_mfma_f32_16x16x32_bf16(af, bv, d, 0, 0, 0);
#pragma unroll
        for (int r = 0; r < 4; ++r)
          out[(size_t)(bN + i0 + quad * 4 + r) * HID_ + h * 64 + nt * 16 + lm] = d[r];
      }
    }
  } else {
    // ---- Fallback (block-uniform; never taken for reference edge pattern) ----
    const int il = tid >> 4;
#pragma unroll
    for (int h = 0; h < NH_; ++h) {
      const u16* qp = Qb + (size_t)(bN + i0 + il) * HID_ + h * 64;
      const u16* kp = Kb + (size_t)(bN + t_own) * HID_ + h * 64;
      float s = 0.f;
      for (int d = 0; d < 64; ++d) s += bf1(qp[d]) * bf1(kp[d]);
      const float qrel = bf1(QRelb[(size_t)(bN + i0 + il) * HID_ + h * 64 + r_own]);
      const float ex = __expf((s - qrel) * 0.125f);
      float den = ex;
      den += __shfl_xor(den, 1);
      den += __shfl_xor(den, 2);
      den += __shfl_xor(den, 4);
      den += __shfl_xor(den, 8);
      p_bf[tid * NH_ + h] = f2bf(ex * __builtin_amdgcn_rcpf(den));
    }
    __syncthreads();
#pragma unroll
    for (int gsub = 0; gsub < 4; ++gsub) {
      const int il2 = w * 4 + gsub;
      float a0[8] = {0.f,0.f,0.f,0.f,0.f,0.f,0.f,0.f};
      float a1[8] = {0.f,0.f,0.f,0.f,0.f,0.f,0.f,0.f};
      for (int j2 = 0; j2 < 16; ++j2) {
        const int t2 = t_s[il2 * 16 + j2];
        const u16* Vrow = Vb + (size_t)(bN + t2) * HID_;
        uint4 v0 = *(const uint4*)(Vrow + lane * 8);
        const float p0 = bf1(p_bf[(il2 * 16 + j2) * NH_ + (lane >> 3)]);
        a0[0] += p0 * bflo(v0.x); a0[1] += p0 * bfhi(v0.x);
        a0[2] += p0 * bflo(v0.y); a0[3] += p0 * bfhi(v0.y);
        a0[4] += p0 * bflo(v0.z); a0[5] += p0 * bfhi(v0.z);
        a0[6] += p0 * bflo(v0.w); a0[7] += p0 * bfhi(v0.w);
        if (lane < 32) {
          uint4 v1 = *(const uint4*)(Vrow + 512 + lane * 8);
          const float p1 = bf1(p_bf[(il2 * 16 + j2) * NH_ + 8 + (lane >> 3)]);
          a1[0] += p1 * bflo(v1.x); a1[1] += p1 * bfhi(v1.x);
          a1[2] += p1 * bflo(v1.y); a1[3] += p1 * bfhi(v1.y);
          a1[4] += p1 * bflo(v1.z); a1[5] += p1 * bfhi(v1.z);
          a1[6] += p1 * bflo(v1.w); a1[7] += p1 * bfhi(v1.w);
        }
      }
      float* orow = out + (size_t)(bN + i0 + il2) * HID_;
      *(float4*)(orow + lane * 8)     = make_float4(a0[0], a0[1], a0[2], a0[3]);
      *(float4*)(orow + lane * 8 + 4) = make_float4(a0[4], a0[5], a0[6], a0[7]);
      if (lane < 32) {
        *(float4*)(orow + 512 + lane * 8)     = make_float4(a1[0], a1[1], a1[2], a1[3]);
        *(float4*)(orow + 512 + lane * 8 + 4) = make_float4(a1[4], a1[5], a1[6], a1[7]);
      }
    }
  }
}

extern "C" void kernel_launch(void* const* d_in, const int* in_sizes, int n_in,
                              void* d_out, int out_size, void* d_ws, size_t ws_size,
                              hipStream_t stream) {
  const float* X   = (const float*)d_in[0];
  const int*   eidx= (const int*)d_in[1];
  const float* Wq  = (const float*)d_in[2];
  const float* bq  = (const float*)d_in[3];
  const float* Wk  = (const float*)d_in[4];
  const float* bk  = (const float*)d_in[5];
  const float* Wv  = (const float*)d_in[6];
  const float* bv  = (const float*)d_in[7];
  const float* rel = (const float*)d_in[8];
  float* out = (float*)d_out;

  char* ws = (char*)d_ws;
  u16* Xbf = (u16*)(ws);
  u16* QRelb = Xbf;                       // overlays Xbf (dead after k_gemm)
  u16* Wbf = (u16*)(ws + 12582912);
  u16* Qb  = (u16*)(ws + 16121856);
  u16* Kb  = (u16*)(ws + 28704768);
  u16* Vb  = (u16*)(ws + 41287680);
  u16* Rbf = (u16*)(ws + 53870592);

  static bool s_attr = false;
  if (!s_attr) {
    (void)hipFuncSetAttribute((const void*)k_gemm,
                              hipFuncAttributeMaxDynamicSharedMemorySize, 139264);
    s_attr = true;
  }

  k_convert<<<7920, 256, 0, stream>>>((const float4*)X, (const float4*)Wq,
                                      (const float4*)Wk, (const float4*)Wv,
                                      (const float4*)rel,
                                      (ushort4*)Xbf, (ushort4*)Wbf, (ushort4*)Rbf);
  k_gemm<<<dim3(32, 8), 512, 139264, stream>>>(Xbf, Wbf, bq, bk, bv, Qb, Kb, Vb);
  k_qrel<<<256, 256, 0, stream>>>(Qb, Rbf, QRelb);
  k_attn<<<512, 256, 0, stream>>>(Qb, Kb, Vb, QRelb, eidx, out);
}

// Round 5
// 145.381 us; speedup vs baseline: 1.2555x; 1.1206x over previous
//
#include <hip/hip_runtime.h>

#define B_    4
#define N_    2048
#define HID_  768
#define NH_   12
#define E_    131072
#define M_    8192   // B_*N_
#define NREL_ 64
#define G_    16     // groups per attn block
#define BAND_ 32     // band width (K/V rows per block)
#define VP_   40     // Vt pitch in u16 (32 slots + 8 pad): 16B-aligned frags, spread banks
#define PP_   40     // p_bf pitch in u16

typedef unsigned short u16;
typedef unsigned int   u32;
typedef short bf16x8 __attribute__((ext_vector_type(8)));
typedef float f32x4  __attribute__((ext_vector_type(4)));

__device__ __forceinline__ u16 f2bf(float x) {
  u32 u = __float_as_uint(x);
  u += 0x7fffu + ((u >> 16) & 1u);   // RNE
  return (u16)(u >> 16);
}
__device__ __forceinline__ float bflo(u32 u) { return __uint_as_float(u << 16); }
__device__ __forceinline__ float bfhi(u32 u) { return __uint_as_float(u & 0xffff0000u); }
__device__ __forceinline__ float bf1(u16 v) { return __uint_as_float(((u32)v) << 16); }

__device__ __forceinline__ void load_lds16(const u16* g, u16* l) {
  __builtin_amdgcn_global_load_lds((__attribute__((address_space(1))) void*)(g),
                                   (__attribute__((address_space(3))) void*)(l),
                                   16, 0, 0);
}

// ---------------- Kernel 0: f32 -> bf16 convert (X, Wq, Wk, Wv, rel) ----------------
// HBM-roofline for its ~47MB of traffic. Frozen.
__global__ __launch_bounds__(256) void k_convert(
    const float4* __restrict__ X, const float4* __restrict__ Wq,
    const float4* __restrict__ Wk, const float4* __restrict__ Wv,
    const float4* __restrict__ rel,
    ushort4* __restrict__ Xbf, ushort4* __restrict__ Wbf, ushort4* __restrict__ Rbf) {
  const int NX4 = (M_ * HID_) / 4;
  const int NW4 = (HID_ * HID_) / 4;
  const int NR4 = (NREL_ * HID_) / 4;
  int tid = blockIdx.x * 256 + threadIdx.x;
  const float4* src; ushort4* dst; int off;
  if (tid < NX4) { src = X; dst = Xbf; off = tid; }
  else if (tid < NX4 + 3 * NW4) {
    int t2 = tid - NX4;
    int wi = t2 / NW4;
    off = t2 - wi * NW4;
    src = (wi == 0) ? Wq : (wi == 1) ? Wk : Wv;
    dst = Wbf + (size_t)wi * NW4;
  } else {
    off = tid - NX4 - 3 * NW4;
    if (off >= NR4) return;
    src = rel; dst = Rbf;
  }
  float4 v = src[off];
  ushort4 o;
  o.x = f2bf(v.x); o.y = f2bf(v.y); o.z = f2bf(v.z); o.w = f2bf(v.w);
  dst[off] = o;
}

// ---------------- Kernel 1: fused QKV GEMM, bf16 MFMA, 128x192 tile ----------------
// R0-frozen structure (2-barrier, 3 blocks/CU implicit overlap). Four phase-pipeline
// restructures (R9-R12) all measured slower on this skinny-K shape. DO NOT TOUCH.
__global__ __launch_bounds__(256, 3) void k_gemm(
    const u16* __restrict__ Xbf, const u16* __restrict__ Wbf,
    const float* __restrict__ bq, const float* __restrict__ bk, const float* __restrict__ bv,
    u16* __restrict__ Qb, u16* __restrict__ Kb, u16* __restrict__ Vb) {
  __shared__ u16 As[128 * 64];   // 16 KB
  __shared__ u16 Bs[192 * 64];   // 24 KB
  const int tid = threadIdx.x;
  const int w = tid >> 6, lane = tid & 63;
  const int m0 = blockIdx.x * 128;
  const int ny = blockIdx.y;            // 0..11
  const int widx = ny >> 2;             // 0:Q 1:K 2:V
  const int nl0 = (ny & 3) * 192;
  const u16* Wp = Wbf + (size_t)widx * (HID_ * HID_);
  u16* Op = (widx == 0) ? Qb : (widx == 1) ? Kb : Vb;
  const float* bias = (widx == 0) ? bq : (widx == 1) ? bk : bv;

  f32x4 acc[4][6] = {};
  const int wm = w >> 1, wn = w & 1;
  const int lm = lane & 15, lg = lane >> 4;

  for (int kt = 0; kt < HID_ / 64; ++kt) {
    const int k0 = kt * 64;
    __syncthreads();
#pragma unroll
    for (int ii = 0; ii < 4; ++ii) {
      const int sb = (ii * 4 + w) * 64;
      const int s = sb + lane;
      const int m = s >> 3;
      const int g = (s & 7) ^ (m & 7);
      load_lds16(Xbf + (size_t)(m0 + m) * HID_ + k0 + g * 8, &As[sb * 8]);
    }
#pragma unroll
    for (int ii = 0; ii < 6; ++ii) {
      const int sb = (ii * 4 + w) * 64;
      const int s = sb + lane;
      const int m = s >> 3;
      const int g = (s & 7) ^ (m & 7);
      load_lds16(Wp + (size_t)(nl0 + m) * HID_ + k0 + g * 8, &Bs[sb * 8]);
    }
    __syncthreads();
#pragma unroll
    for (int kk = 0; kk < 2; ++kk) {
      bf16x8 af[4], bfr[6];
#pragma unroll
      for (int mt = 0; mt < 4; ++mt) {
        const int m = wm * 64 + mt * 16 + lm;
        const int g = (kk * 4 + lg) ^ (m & 7);
        af[mt] = *(const bf16x8*)&As[m * 64 + g * 8];
      }
#pragma unroll
      for (int nt = 0; nt < 6; ++nt) {
        const int n = wn * 96 + nt * 16 + lm;
        const int g = (kk * 4 + lg) ^ (n & 7);
        bfr[nt] = *(const bf16x8*)&Bs[n * 64 + g * 8];
      }
#pragma unroll
      for (int mt = 0; mt < 4; ++mt)
#pragma unroll
        for (int nt = 0; nt < 6; ++nt)
          acc[mt][nt] = __builtin_amdgcn_mfma_f32_16x16x32_bf16(af[mt], bfr[nt], acc[mt][nt], 0, 0, 0);
    }
  }
#pragma unroll
  for (int nt = 0; nt < 6; ++nt) {
    const int c = nl0 + wn * 96 + nt * 16 + lm;
    const float bb = bias[c];
#pragma unroll
    for (int mt = 0; mt < 4; ++mt) {
      const int rbase = m0 + wm * 64 + mt * 16 + lg * 4;
#pragma unroll
      for (int r = 0; r < 4; ++r)
        Op[(size_t)(rbase + r) * HID_ + c] = f2bf(acc[mt][nt][r] + bb);
    }
  }
}

// ---------------- Kernel 2: banded attention + fused QRel ----------------
// R13: k_qrel is FUSED here. Each wave owns 3 heads and already holds the exact
// Q A-fragments (qa) that QRel needs; rel (96KB bf16) is L2-resident. Pre-barrier-A
// each wave computes QRel[16 q-rows][64 rels] per head with 24 MFMA (bit-identical
// arithmetic to the old k_qrel) and scatters bf16 results into a 24KB LDS scratch
// OVERLAYING Vt (dead until the post-A scatter), layout qs[head][rel][il]. After
// barrier A (r_s visible) the 12 needed values are gathered with ds_read_u16;
// barrier A2 fences the overlay reads from the Vt overwrite. Saves the k_qrel
// dispatch + its 25MB HBM round-trip + the QRelb buffer.
__global__ __launch_bounds__(256, 2) void k_attn(
    const u16* __restrict__ Qb, const u16* __restrict__ Kb, const u16* __restrict__ Vb,
    const u16* __restrict__ Rbf, const int* __restrict__ eidx,
    float* __restrict__ out) {
  __shared__ __align__(16) u16 Vt[HID_ * VP_];       // 61,440B (first 24,576B: qs overlay)
  __shared__ __align__(16) u16 p_bf[NH_ * 16 * PP_]; // 15,360B
  __shared__ u16 r_s[256];
  __shared__ int t_s[256];
  __shared__ int badf;

  const int tid = threadIdx.x;
  const int w = tid >> 6, lane = tid & 63;
  const int lm = lane & 15, quad = lane >> 4;
  const int e0b = blockIdx.x * 256;
  const int b  = eidx[e0b];
  const int i0 = eidx[E_ + e0b];
  const int bN = b * N_;

  // ---- V prefetch into VGPRs (48 VGPR), transpose-store mapping ----
  const int sV = tid & 31, pV = tid >> 5;
  const int rowV = (i0 + 1 + sV) & (N_ - 1);
  const u16* srcV = Vb + (size_t)(bN + rowV) * HID_ + pV * 96;
  uint4 vv[12];
#pragma unroll
  for (int c = 0; c < 12; ++c) vv[c] = *(const uint4*)(srcV + c * 8);

  // ---- Q + K fragments direct from global (B-frag layout, 16B/lane) ----
  const u16* Qrow  = Qb + (size_t)(bN + i0 + lm) * HID_ + quad * 8;
  const u16* Krow0 = Kb + (size_t)(bN + ((i0 + 1 + lm) & (N_ - 1))) * HID_ + quad * 8;
  const u16* Krow1 = Kb + (size_t)(bN + ((i0 + 17 + lm) & (N_ - 1))) * HID_ + quad * 8;
  bf16x8 qa[3][2], ka[3][4];
#pragma unroll
  for (int hh = 0; hh < 3; ++hh) {
    const int o = (w * 3 + hh) * 64;
    qa[hh][0] = *(const bf16x8*)(Qrow + o);
    qa[hh][1] = *(const bf16x8*)(Qrow + o + 32);
    ka[hh][0] = *(const bf16x8*)(Krow0 + o);
    ka[hh][1] = *(const bf16x8*)(Krow0 + o + 32);
    ka[hh][2] = *(const bf16x8*)(Krow1 + o);
    ka[hh][3] = *(const bf16x8*)(Krow1 + o + 32);
  }

  // ---- P0: publish t/r, zero p_bf, band-pattern check ----
  const int t_own = eidx[2 * E_ + e0b + tid];
  const int r_own = eidx[3 * E_ + e0b + tid];
  t_s[tid] = t_own;
  r_s[tid] = (u16)r_own;
  if (tid == 0) badf = 0;
  {
    u32* pz = (u32*)p_bf;
#pragma unroll
    for (int z = 0; z < NH_ * 16 * PP_ / 2 / 256; ++z) pz[z * 256 + tid] = 0;
    const int expect = (i0 + (tid >> 4) + (tid & 15) + 1) & (N_ - 1);
    if (t_own != expect) badf = 1;
  }

  // ---- Fused QRel: per wave, 3 heads x (16 rows x 64 rels) via MFMA -> qs overlay.
  // Arithmetic bit-identical to the old k_qrel (same operands, same 2-MFMA chain,
  // same f2bf). Wave-local LDS region; drained by barrier A.
#pragma unroll
  for (int hh = 0; hh < 3; ++hh) {
    const int h = w * 3 + hh;
    const u16* rp = Rbf + h * 64 + quad * 8;
    u16* qsh = (u16*)Vt + h * 1024;          // [rel][il], 1024 u16 per head
#pragma unroll
    for (int rt = 0; rt < 4; ++rt) {
      const u16* rr = rp + (size_t)(rt * 16 + lm) * HID_;
      bf16x8 rb0 = *(const bf16x8*)(rr);
      bf16x8 rb1 = *(const bf16x8*)(rr + 32);
      f32x4 cc = {0.f, 0.f, 0.f, 0.f};
      cc = __builtin_amdgcn_mfma_f32_16x16x32_bf16(qa[hh][0], rb0, cc, 0, 0, 0);
      cc = __builtin_amdgcn_mfma_f32_16x16x32_bf16(qa[hh][1], rb1, cc, 0, 0, 0);
      uint2 pk;
      pk.x = (u32)f2bf(cc[0]) | ((u32)f2bf(cc[1]) << 16);
      pk.y = (u32)f2bf(cc[2]) | ((u32)f2bf(cc[3]) << 16);
      *(uint2*)&qsh[(rt * 16 + lm) * 16 + quad * 4] = pk;   // 8B-aligned b64 write
    }
  }

  __syncthreads();   // barrier A: publishes LDS (incl. qs) + drains ALL global loads
  const int bad = badf;

  if (!bad) {
    // ---- QRel gather from LDS scratch (r_s now visible) ----
    int eidx4[4]; float qrelv[3][4];
#pragma unroll
    for (int r = 0; r < 4; ++r) {
      const int il = quad * 4 + r;
      eidx4[r] = il * 16 + ((lm - il) & 15);
    }
#pragma unroll
    for (int hh = 0; hh < 3; ++hh) {
      const int h = w * 3 + hh;
#pragma unroll
      for (int r = 0; r < 4; ++r) {
        const int il = quad * 4 + r;
        qrelv[hh][r] = bf1(((const u16*)Vt)[h * 1024 + (int)r_s[eidx4[r]] * 16 + il]);
      }
    }
    __syncthreads();   // barrier A2: all qs gathers complete before Vt overwrite

    // ---- Vt scatter from registers (2-way banks, free) ----
#pragma unroll
    for (int c = 0; c < 12; ++c) {
      uint4 v = vv[c];
      const int d0 = pV * 96 + c * 8;
      Vt[(d0 + 0) * VP_ + sV] = (u16)(v.x);
      Vt[(d0 + 1) * VP_ + sV] = (u16)(v.x >> 16);
      Vt[(d0 + 2) * VP_ + sV] = (u16)(v.y);
      Vt[(d0 + 3) * VP_ + sV] = (u16)(v.y >> 16);
      Vt[(d0 + 4) * VP_ + sV] = (u16)(v.z);
      Vt[(d0 + 5) * VP_ + sV] = (u16)(v.z >> 16);
      Vt[(d0 + 6) * VP_ + sV] = (u16)(v.w);
      Vt[(d0 + 7) * VP_ + sV] = (u16)(v.w >> 16);
    }

    // ---- QK^T MFMA (all-register operands) + in-register softmax -> p_bf ----
#pragma unroll
    for (int hh = 0; hh < 3; ++hh) {
      const int h = w * 3 + hh;
      f32x4 c0 = {0.f, 0.f, 0.f, 0.f}, c1 = {0.f, 0.f, 0.f, 0.f};
      c0 = __builtin_amdgcn_mfma_f32_16x16x32_bf16(qa[hh][0], ka[hh][0], c0, 0, 0, 0);
      c0 = __builtin_amdgcn_mfma_f32_16x16x32_bf16(qa[hh][1], ka[hh][1], c0, 0, 0, 0);
      c1 = __builtin_amdgcn_mfma_f32_16x16x32_bf16(qa[hh][0], ka[hh][2], c1, 0, 0, 0);
      c1 = __builtin_amdgcn_mfma_f32_16x16x32_bf16(qa[hh][1], ka[hh][3], c1, 0, 0, 0);
#pragma unroll
      for (int r = 0; r < 4; ++r) {
        const int il = quad * 4 + r;
        const float val = (lm >= il) ? c0[r] : c1[r];
        const float ex = __expf((val - qrelv[hh][r]) * 0.125f);
        float den = ex;
        den += __shfl_xor(den, 1);
        den += __shfl_xor(den, 2);
        den += __shfl_xor(den, 4);
        den += __shfl_xor(den, 8);
        const float p = ex * __builtin_amdgcn_rcpf(den);
        const int slot = il + ((lm - il) & 15);
        p_bf[(h * 16 + il) * PP_ + slot] = f2bf(p);
      }
    }
    __syncthreads();   // barrier B: Vt + p_bf complete

    // ---- PV: out = P @ Vband via MFMA ----
#pragma unroll
    for (int hh = 0; hh < 3; ++hh) {
      const int h = w * 3 + hh;
      bf16x8 af = *(const bf16x8*)&p_bf[(h * 16 + lm) * PP_ + quad * 8];
#pragma unroll
      for (int nt = 0; nt < 4; ++nt) {
        bf16x8 bv = *(const bf16x8*)&Vt[(h * 64 + nt * 16 + lm) * VP_ + quad * 8];
        f32x4 d = {0.f, 0.f, 0.f, 0.f};
        d = __builtin_amdgcn_mfma_f32_16x16x32_bf16(af, bv, d, 0, 0, 0);
#pragma unroll
        for (int r = 0; r < 4; ++r)
          out[(size_t)(bN + i0 + quad * 4 + r) * HID_ + h * 64 + nt * 16 + lm] = d[r];
      }
    }
  } else {
    // ---- Fallback (block-uniform; never taken for reference edge pattern) ----
    const int il = tid >> 4;
#pragma unroll
    for (int h = 0; h < NH_; ++h) {
      const u16* qp = Qb + (size_t)(bN + i0 + il) * HID_ + h * 64;
      const u16* kp = Kb + (size_t)(bN + t_own) * HID_ + h * 64;
      const u16* rp = Rbf + (size_t)r_own * HID_ + h * 64;
      float s = 0.f, qr = 0.f;
      for (int d = 0; d < 64; ++d) {
        s  += bf1(qp[d]) * bf1(kp[d]);
        qr += bf1(qp[d]) * bf1(rp[d]);
      }
      const float ex = __expf((s - qr) * 0.125f);
      float den = ex;
      den += __shfl_xor(den, 1);
      den += __shfl_xor(den, 2);
      den += __shfl_xor(den, 4);
      den += __shfl_xor(den, 8);
      p_bf[tid * NH_ + h] = f2bf(ex * __builtin_amdgcn_rcpf(den));
    }
    __syncthreads();
#pragma unroll
    for (int gsub = 0; gsub < 4; ++gsub) {
      const int il2 = w * 4 + gsub;
      float a0[8] = {0.f,0.f,0.f,0.f,0.f,0.f,0.f,0.f};
      float a1[8] = {0.f,0.f,0.f,0.f,0.f,0.f,0.f,0.f};
      for (int j2 = 0; j2 < 16; ++j2) {
        const int t2 = t_s[il2 * 16 + j2];
        const u16* Vrow = Vb + (size_t)(bN + t2) * HID_;
        uint4 v0 = *(const uint4*)(Vrow + lane * 8);
        const float p0 = bf1(p_bf[(il2 * 16 + j2) * NH_ + (lane >> 3)]);
        a0[0] += p0 * bflo(v0.x); a0[1] += p0 * bfhi(v0.x);
        a0[2] += p0 * bflo(v0.y); a0[3] += p0 * bfhi(v0.y);
        a0[4] += p0 * bflo(v0.z); a0[5] += p0 * bfhi(v0.z);
        a0[6] += p0 * bflo(v0.w); a0[7] += p0 * bfhi(v0.w);
        if (lane < 32) {
          uint4 v1 = *(const uint4*)(Vrow + 512 + lane * 8);
          const float p1 = bf1(p_bf[(il2 * 16 + j2) * NH_ + 8 + (lane >> 3)]);
          a1[0] += p1 * bflo(v1.x); a1[1] += p1 * bfhi(v1.x);
          a1[2] += p1 * bflo(v1.y); a1[3] += p1 * bfhi(v1.y);
          a1[4] += p1 * bflo(v1.z); a1[5] += p1 * bfhi(v1.z);
          a1[6] += p1 * bflo(v1.w); a1[7] += p1 * bfhi(v1.w);
        }
      }
      float* orow = out + (size_t)(bN + i0 + il2) * HID_;
      *(float4*)(orow + lane * 8)     = make_float4(a0[0], a0[1], a0[2], a0[3]);
      *(float4*)(orow + lane * 8 + 4) = make_float4(a0[4], a0[5], a0[6], a0[7]);
      if (lane < 32) {
        *(float4*)(orow + 512 + lane * 8)     = make_float4(a1[0], a1[1], a1[2], a1[3]);
        *(float4*)(orow + 512 + lane * 8 + 4) = make_float4(a1[4], a1[5], a1[6], a1[7]);
      }
    }
  }
}

extern "C" void kernel_launch(void* const* d_in, const int* in_sizes, int n_in,
                              void* d_out, int out_size, void* d_ws, size_t ws_size,
                              hipStream_t stream) {
  const float* X   = (const float*)d_in[0];
  const int*   eidx= (const int*)d_in[1];
  const float* Wq  = (const float*)d_in[2];
  const float* bq  = (const float*)d_in[3];
  const float* Wk  = (const float*)d_in[4];
  const float* bk  = (const float*)d_in[5];
  const float* Wv  = (const float*)d_in[6];
  const float* bv  = (const float*)d_in[7];
  const float* rel = (const float*)d_in[8];
  float* out = (float*)d_out;

  char* ws = (char*)d_ws;
  u16* Xbf = (u16*)(ws);
  u16* Wbf = (u16*)(ws + 12582912);
  u16* Qb  = (u16*)(ws + 16121856);
  u16* Kb  = (u16*)(ws + 28704768);
  u16* Vb  = (u16*)(ws + 41287680);
  u16* Rbf = (u16*)(ws + 53870592);

  k_convert<<<7920, 256, 0, stream>>>((const float4*)X, (const float4*)Wq,
                                      (const float4*)Wk, (const float4*)Wv,
                                      (const float4*)rel,
                                      (ushort4*)Xbf, (ushort4*)Wbf, (ushort4*)Rbf);
  k_gemm<<<dim3(64, 12), 256, 0, stream>>>(Xbf, Wbf, bq, bk, bv, Qb, Kb, Vb);
  k_attn<<<512, 256, 0, stream>>>(Qb, Kb, Vb, Rbf, eidx, out);
}